// Round 4
// baseline (660.231 us; speedup 1.0000x reference)
//
#include <hip/hip_runtime.h>
#include <hip/hip_bf16.h>

// Problem: VOCAB=30522, TYPES=2, D0=64, D1=768, D2=64, MAXOFF=64, GLOB=64,
// B=8, S=512, EPS=1e-12.
//
// ESTABLISHED (R0-R3 journal):
//  * Inputs: FP32, setup_inputs() dict order. Proof: R3's size-switch took the
//    dict branch and the dtype sniff chose fp32 (R3 output bit-identical to
//    R2); reading these buffers as bf16 gave NaN (R1).
//  * Output buffer: FP32 (reference returns jnp.float32; harness "bf16" label
//    is the comparison domain, not buffer dtype). Writing bf16 pairs into it
//    produced the index-scrambled error 5.921875 seen identically in R2+R3.
//  * Comparison: expected quantized to bf16, threshold 0.103 (floor_eps_k=8).
#define S_ 512
#define D1_ 768

// out layout (fp32 elements, concatenated in return order):
//   embd0 [8,64,64]      at 0        (32768)
//   embd1 [8,512,768]    at 32768    (3145728)
//   embd2 [8,512,512,64] at 3178496  (134217728)

__device__ __forceinline__ float wsum(float v) {
#pragma unroll
    for (int o = 32; o; o >>= 1) v += __shfl_xor(v, o);
    return v;
}

// ---------------------------------------------------------------------------
// K0: embd0 = LN(W_glob) broadcast to 8 batches; 130-row LN'd W_rel table ->
// ws (fp32). One wave per 64-elem row. blocks 0..63 -> W_glob, 64..193 -> W_rel.
__global__ __launch_bounds__(64) void k_small(const float* __restrict__ Wg,
                                              const float* __restrict__ Wr,
                                              float* __restrict__ out0,
                                              float* __restrict__ table) {
    int t = threadIdx.x;
    int bid = blockIdx.x;
    float v = (bid < 64) ? Wg[bid * 64 + t] : Wr[(bid - 64) * 64 + t];
    float m = wsum(v) * (1.f / 64.f);
    float d = v - m;
    float q = wsum(d * d) * (1.f / 64.f);
    float o = d * rsqrtf(q + 1e-12f);
    if (bid < 64) {
#pragma unroll
        for (int b = 0; b < 8; b++) out0[b * 4096 + bid * 64 + t] = o;
    } else {
        table[(bid - 64) * 64 + t] = o;
    }
}

// ---------------------------------------------------------------------------
// K1: one block per (b,s). raw = W_word[tok]+W_type[ty]+W_abs[s]; out1 =
// LN(raw) fp32; raw also stored fp32 to ws for the diag2 matmul kernel.
__global__ __launch_bounds__(256) void k_embd1(const int* __restrict__ tok,
                                               const int* __restrict__ tty,
                                               const float* __restrict__ Ww,
                                               const float* __restrict__ Wt,
                                               const float* __restrict__ Wa,
                                               float* __restrict__ out1,
                                               float* __restrict__ rawout) {
    __shared__ float ssum[4], ssq[4];
    int t = threadIdx.x;
    int bs = blockIdx.x;  // b*512 + s
    int s = bs & (S_ - 1);
    size_t wrow = (size_t)tok[bs] * D1_;
    int trow = tty[bs] * D1_;
    int arow = s * D1_;
    float v0 = Ww[wrow + t]       + Wt[trow + t]       + Wa[arow + t];
    float v1 = Ww[wrow + t + 256] + Wt[trow + t + 256] + Wa[arow + t + 256];
    float v2 = Ww[wrow + t + 512] + Wt[trow + t + 512] + Wa[arow + t + 512];
    float ls = v0 + v1 + v2;
    float lq = v0 * v0 + v1 * v1 + v2 * v2;
    float s1 = wsum(ls), q1 = wsum(lq);
    int w = t >> 6;
    if ((t & 63) == 0) { ssum[w] = s1; ssq[w] = q1; }
    __syncthreads();
    float Sa = ssum[0] + ssum[1] + ssum[2] + ssum[3];
    float Qa = ssq[0] + ssq[1] + ssq[2] + ssq[3];
    float mean = Sa * (1.f / 768.f);
    float var = Qa * (1.f / 768.f) - mean * mean;
    float rstd = rsqrtf(var + 1e-12f);
    size_t ob = (size_t)bs * D1_;
    out1[ob + t]       = (v0 - mean) * rstd;
    out1[ob + t + 256] = (v1 - mean) * rstd;
    out1[ob + t + 512] = (v2 - mean) * rstd;
    rawout[ob + t] = v0;
    rawout[ob + t + 256] = v1;
    rawout[ob + t + 512] = v2;
}

// ---------------------------------------------------------------------------
// K1b: diag2[4096,64] = raw[4096,768] @ Wd[64,768]^T + bd. Tiled 16 rows x 64
// cols per block so Wd stays L2-resident (~64 total passes, not 4096).
__global__ __launch_bounds__(256) void k_diagmm(const float* __restrict__ rawS,
                                                const float* __restrict__ Wd,
                                                const float* __restrict__ bd,
                                                float* __restrict__ diag2) {
    __shared__ float rawT[1024];      // 16 rows x 64 k
    __shared__ float wdT[64 * 65];    // k x col, padded
    int t = threadIdx.x;
    int r0 = blockIdx.x * 16;
    int c = t & 63, rq = t >> 6;
    float a0 = 0.f, a1 = 0.f, a2 = 0.f, a3 = 0.f;
    for (int k0 = 0; k0 < 768; k0 += 64) {
        for (int x = t; x < 1024; x += 256)
            rawT[x] = rawS[(r0 + (x >> 6)) * 768 + k0 + (x & 63)];
        for (int x = t; x < 4096; x += 256) {
            int cc = x >> 6, kk = x & 63;
            wdT[kk * 65 + cc] = Wd[cc * 768 + k0 + kk];
        }
        __syncthreads();
#pragma unroll 16
        for (int kk = 0; kk < 64; kk++) {
            float wv = wdT[kk * 65 + c];
            a0 += rawT[rq * 64 + kk] * wv;
            a1 += rawT[(rq + 4) * 64 + kk] * wv;
            a2 += rawT[(rq + 8) * 64 + kk] * wv;
            a3 += rawT[(rq + 12) * 64 + kk] * wv;
        }
        __syncthreads();
    }
    float b = bd[c];
    diag2[(r0 + rq) * 64 + c] = a0 + b;
    diag2[(r0 + rq + 4) * 64 + c] = a1 + b;
    diag2[(r0 + rq + 8) * 64 + c] = a2 + b;
    diag2[(r0 + rq + 12) * 64 + c] = a3 + b;
}

// ---------------------------------------------------------------------------
// K2: embd2 streamer. One block per (b,i); lanes copy 16B chunks of the LN'd
// fp32 table row (256 B) picked by the rpe id. Pure write bandwidth.
// id: (i==0,j>0)->128; (i>0,j==0)->129; diff-type->64; d=i-j: d==0->0;
// d>0 -> 128-min(d,63); d<0 -> min(-d,63). Diagonal fixed afterwards by K3.
__global__ __launch_bounds__(256) void k_embd2(const int* __restrict__ tty,
                                               const uint4* __restrict__ table,
                                               uint4* __restrict__ out2) {
    __shared__ int ty[S_];
    int t = threadIdx.x;
    int bi = blockIdx.x;  // b*512 + i
    int b = bi >> 9, i = bi & (S_ - 1);
    for (int j = t; j < S_; j += 256) ty[j] = tty[b * S_ + j];
    __syncthreads();
    int ti = ty[i];
    int sub = t & 15;       // 16 uint4 per 64-fp32 row
    int jbase = t >> 4;     // 16 rows per pass
    size_t obase = (size_t)bi * (S_ * 16);  // uint4 index of (b,i,j=0)
#pragma unroll
    for (int it = 0; it < 32; it++) {
        int j = it * 16 + jbase;
        int d = i - j;
        int id;
        if (i == 0 && j > 0)      id = 128;
        else if (j == 0 && i > 0) id = 129;
        else if (ty[j] != ti)     id = 64;
        else if (d == 0)          id = 0;
        else if (d > 0)           id = 128 - (d < 63 ? d : 63);
        else { int nd = -d;       id = (nd < 63 ? nd : 63); }
        out2[obase + (size_t)j * 16 + sub] = table[id * 16 + sub];
    }
}

// ---------------------------------------------------------------------------
// K3: overwrite the 4096 diagonal rows: LN(W_rel[0] + diag2[b,i]). One wave
// per row.
__global__ __launch_bounds__(64) void k_diag(const float* __restrict__ Wr,
                                             const float* __restrict__ diag2,
                                             float* __restrict__ out2) {
    int t = threadIdx.x;
    int r = blockIdx.x;  // b*512 + i
    int i = r & (S_ - 1);
    float v = Wr[t] + diag2[r * 64 + t];
    float m = wsum(v) * (1.f / 64.f);
    float d = v - m;
    float q = wsum(d * d) * (1.f / 64.f);
    out2[((size_t)r * S_ + i) * 64 + t] = d * rsqrtf(q + 1e-12f);
}

extern "C" void kernel_launch(void* const* d_in, const int* in_sizes, int n_in,
                              void* d_out, int out_size, void* d_ws, size_t ws_size,
                              hipStream_t stream) {
    // Dict order (confirmed R3): tok(4096) tty(4096) Ww(23440896) Wt(1536)
    // Wa(393216) Wr(8320) Wg(4096) Wd(49152) bd(64).
    const int* tok  = (const int*)d_in[0];
    const int* tty  = (const int*)d_in[1];
    const float* Ww = (const float*)d_in[2];
    const float* Wt = (const float*)d_in[3];
    const float* Wa = (const float*)d_in[4];
    const float* Wr = (const float*)d_in[5];
    const float* Wg = (const float*)d_in[6];
    const float* Wd = (const float*)d_in[7];
    const float* bd = (const float*)d_in[8];

    float* out  = (float*)d_out;
    float* out0 = out;
    float* out1 = out + 32768;
    float* out2 = out + 3178496;

    // ws: table fp32 @0 (33,280B); diag2 fp32 @65536 (1MB); raw fp32 @1114112
    // (12.6MB). Total ~13.7MB.
    float* table = (float*)d_ws;
    float* diag2 = (float*)((char*)d_ws + 65536);
    float* rawws = (float*)((char*)d_ws + 1114112);

    hipLaunchKernelGGL(k_small, dim3(194), dim3(64), 0, stream, Wg, Wr, out0, table);
    hipLaunchKernelGGL(k_embd1, dim3(4096), dim3(256), 0, stream,
                       tok, tty, Ww, Wt, Wa, out1, rawws);
    hipLaunchKernelGGL(k_diagmm, dim3(256), dim3(256), 0, stream,
                       rawws, Wd, bd, diag2);
    hipLaunchKernelGGL(k_embd2, dim3(4096), dim3(256), 0, stream,
                       tty, (const uint4*)table, (uint4*)out2);
    hipLaunchKernelGGL(k_diag, dim3(4096), dim3(64), 0, stream, Wr, diag2, out2);
}

// Round 6
// 652.287 us; speedup vs baseline: 1.0122x; 1.0122x over previous
//
#include <hip/hip_runtime.h>
#include <hip/hip_bf16.h>

// Problem: VOCAB=30522, TYPES=2, D0=64, D1=768, D2=64, MAXOFF=64, GLOB=64,
// B=8, S=512, EPS=1e-12.
//
// ESTABLISHED (R0-R5 journal):
//  * Inputs: FP32, setup_inputs() dict order. Outputs: FP32 buffer, compared
//    after bf16 quantization (threshold 0.103). R4 passed, absmax 0.0078.
//  * R4 dur_us=660 with all top-5 rocprof rows = harness 0xAA poison fills
//    (~350us, 2.2GB each) -> each of our kernels < 348us. Roofline for the
//    mandatory 536MB embd2 write @6.2TB/s is ~87us.
//  * R5: __builtin_nontemporal_store needs clang ext_vector_type, not HIP's
//    uint4 class -> v4u alias below.
#define S_ 512
#define D1_ 768

typedef unsigned int v4u __attribute__((ext_vector_type(4)));

// out layout (fp32 elements, concatenated in return order):
//   embd0 [8,64,64]      at 0        (32768)
//   embd1 [8,512,768]    at 32768    (3145728)
//   embd2 [8,512,512,64] at 3178496  (134217728)

__device__ __forceinline__ float wsum(float v) {
#pragma unroll
    for (int o = 32; o; o >>= 1) v += __shfl_xor(v, o);
    return v;
}

// ---------------------------------------------------------------------------
// K0: embd0 = LN(W_glob) broadcast to 8 batches; 130-row LN'd W_rel table ->
// ws (fp32). One wave per 64-elem row. blocks 0..63 -> W_glob, 64..193 -> W_rel.
__global__ __launch_bounds__(64) void k_small(const float* __restrict__ Wg,
                                              const float* __restrict__ Wr,
                                              float* __restrict__ out0,
                                              float* __restrict__ table) {
    int t = threadIdx.x;
    int bid = blockIdx.x;
    float v = (bid < 64) ? Wg[bid * 64 + t] : Wr[(bid - 64) * 64 + t];
    float m = wsum(v) * (1.f / 64.f);
    float d = v - m;
    float q = wsum(d * d) * (1.f / 64.f);
    float o = d * rsqrtf(q + 1e-12f);
    if (bid < 64) {
#pragma unroll
        for (int b = 0; b < 8; b++) out0[b * 4096 + bid * 64 + t] = o;
    } else {
        table[(bid - 64) * 64 + t] = o;
    }
}

// ---------------------------------------------------------------------------
// K1: one block per (b,s). raw = W_word[tok]+W_type[ty]+W_abs[s]; out1 =
// LN(raw) fp32; raw also stored fp32 to ws for the diag matmul kernel.
__global__ __launch_bounds__(256) void k_embd1(const int* __restrict__ tok,
                                               const int* __restrict__ tty,
                                               const float* __restrict__ Ww,
                                               const float* __restrict__ Wt,
                                               const float* __restrict__ Wa,
                                               float* __restrict__ out1,
                                               float* __restrict__ rawout) {
    __shared__ float ssum[4], ssq[4];
    int t = threadIdx.x;
    int bs = blockIdx.x;  // b*512 + s
    int s = bs & (S_ - 1);
    size_t wrow = (size_t)tok[bs] * D1_;
    int trow = tty[bs] * D1_;
    int arow = s * D1_;
    float v0 = Ww[wrow + t]       + Wt[trow + t]       + Wa[arow + t];
    float v1 = Ww[wrow + t + 256] + Wt[trow + t + 256] + Wa[arow + t + 256];
    float v2 = Ww[wrow + t + 512] + Wt[trow + t + 512] + Wa[arow + t + 512];
    float ls = v0 + v1 + v2;
    float lq = v0 * v0 + v1 * v1 + v2 * v2;
    float s1 = wsum(ls), q1 = wsum(lq);
    int w = t >> 6;
    if ((t & 63) == 0) { ssum[w] = s1; ssq[w] = q1; }
    __syncthreads();
    float Sa = ssum[0] + ssum[1] + ssum[2] + ssum[3];
    float Qa = ssq[0] + ssq[1] + ssq[2] + ssq[3];
    float mean = Sa * (1.f / 768.f);
    float var = Qa * (1.f / 768.f) - mean * mean;
    float rstd = rsqrtf(var + 1e-12f);
    size_t ob = (size_t)bs * D1_;
    out1[ob + t]       = (v0 - mean) * rstd;
    out1[ob + t + 256] = (v1 - mean) * rstd;
    out1[ob + t + 512] = (v2 - mean) * rstd;
    rawout[ob + t] = v0;
    rawout[ob + t + 256] = v1;
    rawout[ob + t + 512] = v2;
}

// ---------------------------------------------------------------------------
// K1b: diag2 = raw[4096,768] @ Wd[64,768]^T + bd, then (fused) LN(W_rel[0] +
// diag2) -> diagLN[4096,64] fp32 in ws. Tiled 16 rows x 64 cols per block;
// each output row is held by exactly one wave (64 lanes) -> wsum LN in-place.
__global__ __launch_bounds__(256) void k_diagmm(const float* __restrict__ rawS,
                                                const float* __restrict__ Wd,
                                                const float* __restrict__ bd,
                                                const float* __restrict__ Wr,
                                                float* __restrict__ diagLN) {
    __shared__ float rawT[1024];      // 16 rows x 64 k
    __shared__ float wdT[64 * 65];    // k x col, padded
    int t = threadIdx.x;
    int r0 = blockIdx.x * 16;
    int c = t & 63, rq = t >> 6;
    float a0 = 0.f, a1 = 0.f, a2 = 0.f, a3 = 0.f;
    for (int k0 = 0; k0 < 768; k0 += 64) {
        for (int x = t; x < 1024; x += 256)
            rawT[x] = rawS[(r0 + (x >> 6)) * 768 + k0 + (x & 63)];
        for (int x = t; x < 4096; x += 256) {
            int cc = x >> 6, kk = x & 63;
            wdT[kk * 65 + cc] = Wd[cc * 768 + k0 + kk];
        }
        __syncthreads();
#pragma unroll 16
        for (int kk = 0; kk < 64; kk++) {
            float wv = wdT[kk * 65 + c];
            a0 += rawT[rq * 64 + kk] * wv;
            a1 += rawT[(rq + 4) * 64 + kk] * wv;
            a2 += rawT[(rq + 8) * 64 + kk] * wv;
            a3 += rawT[(rq + 12) * 64 + kk] * wv;
        }
        __syncthreads();
    }
    float bb = bd[c];
    float w0 = Wr[c];  // W_rel row 0 (the diagonal's base embedding)
    float acc[4] = {a0, a1, a2, a3};
#pragma unroll
    for (int m = 0; m < 4; m++) {
        float v = acc[m] + bb + w0;
        float mean = wsum(v) * (1.f / 64.f);
        float d = v - mean;
        float q = wsum(d * d) * (1.f / 64.f);
        diagLN[(r0 + rq + 4 * m) * 64 + c] = d * rsqrtf(q + 1e-12f);
    }
}

// ---------------------------------------------------------------------------
// K2: embd2 streamer. One block per (b,i); groups of 16 lanes copy one 256B
// fp32 row per j: the LN'd table row picked by the rpe id, or the fused
// diagLN row when j==i. Nontemporal stores (536MB pure stream, never re-read).
// id: diag->diagLN; (i==0,j>0)->128; (i>0,j==0)->129; diff-type->64;
// d=i-j>0 -> 128-min(d,63); d<0 -> min(-d,63).
__global__ __launch_bounds__(256) void k_embd2(const int* __restrict__ tty,
                                               const v4u* __restrict__ table,
                                               const v4u* __restrict__ diagLN,
                                               v4u* __restrict__ out2) {
    __shared__ int ty[S_];
    int t = threadIdx.x;
    int bi = blockIdx.x;  // b*512 + i
    int b = bi >> 9, i = bi & (S_ - 1);
    for (int j = t; j < S_; j += 256) ty[j] = tty[b * S_ + j];
    __syncthreads();
    int ti = ty[i];
    int sub = t & 15;       // 16 v4u per 64-fp32 row
    int jbase = t >> 4;     // 16 rows per pass
    size_t obase = (size_t)bi * (S_ * 16);  // v4u index of (b,i,j=0)
    const v4u* drow = diagLN + (size_t)bi * 16;
#pragma unroll 8
    for (int it = 0; it < 32; it++) {
        int j = it * 16 + jbase;
        int d = i - j;
        const v4u* src;
        if (d == 0)           src = drow;               // diagonal (incl. 0,0)
        else if (i == 0)      src = table + 128 * 16;   // row 0, j>0
        else if (j == 0)      src = table + 129 * 16;   // col 0, i>0
        else if (ty[j] != ti) src = table + 64 * 16;    // cross-segment
        else if (d > 0)       src = table + (128 - (d < 63 ? d : 63)) * 16;
        else { int nd = -d;   src = table + (nd < 63 ? nd : 63) * 16; }
        __builtin_nontemporal_store(src[sub], &out2[obase + (size_t)j * 16 + sub]);
    }
}

extern "C" void kernel_launch(void* const* d_in, const int* in_sizes, int n_in,
                              void* d_out, int out_size, void* d_ws, size_t ws_size,
                              hipStream_t stream) {
    // Dict order (confirmed R3/R4): tok(4096) tty(4096) Ww(23440896) Wt(1536)
    // Wa(393216) Wr(8320) Wg(4096) Wd(49152) bd(64).
    const int* tok  = (const int*)d_in[0];
    const int* tty  = (const int*)d_in[1];
    const float* Ww = (const float*)d_in[2];
    const float* Wt = (const float*)d_in[3];
    const float* Wa = (const float*)d_in[4];
    const float* Wr = (const float*)d_in[5];
    const float* Wg = (const float*)d_in[6];
    const float* Wd = (const float*)d_in[7];
    const float* bd = (const float*)d_in[8];

    float* out  = (float*)d_out;
    float* out0 = out;
    float* out1 = out + 32768;
    float* out2 = out + 3178496;

    // ws: table fp32 @0 (33,280B); diagLN fp32 @65536 (1MB); raw fp32
    // @2097152 (12.6MB). Total ~14.7MB.
    float* table  = (float*)d_ws;
    float* diagLN = (float*)((char*)d_ws + 65536);
    float* rawws  = (float*)((char*)d_ws + 2097152);

    hipLaunchKernelGGL(k_small, dim3(194), dim3(64), 0, stream, Wg, Wr, out0, table);
    hipLaunchKernelGGL(k_embd1, dim3(4096), dim3(256), 0, stream,
                       tok, tty, Ww, Wt, Wa, out1, rawws);
    hipLaunchKernelGGL(k_diagmm, dim3(256), dim3(256), 0, stream,
                       rawws, Wd, bd, Wr, diagLN);
    hipLaunchKernelGGL(k_embd2, dim3(4096), dim3(256), 0, stream,
                       tty, (const v4u*)table, (const v4u*)diagLN, (v4u*)out2);
}